// Round 1
// baseline (412.211 us; speedup 1.0000x reference)
//
#include <hip/hip_runtime.h>
#include <math.h>

// Problem constants (B,P,V,F,H) = (32,512,32,16,64)
namespace {
constexpr int kV = 32;
constexpr int kF = 16;
constexpr int kH = 64;
constexpr int kK = 128;   // 2H, input width of layers 2/3
constexpr float kSlope = 0.01f;

__device__ __forceinline__ float lrelu(float x) {
    // x>0 ? x : 0.01x  ==  max(x, 0.01x) for slope in (0,1)
    return fmaxf(x, kSlope * x);
}

__device__ __forceinline__ float dot4(float4 w, float4 x, float a) {
    a = fmaf(w.x, x.x, a);
    a = fmaf(w.y, x.y, a);
    a = fmaf(w.z, x.z, a);
    a = fmaf(w.w, x.w, a);
    return a;
}

// One block per (b,p). 256 threads.
// Lane mapping: ha = t&31, hb = ha+32 (two output channels),
//               vg = t>>5 (0..7), v = vg*4 + {0..3} (four V rows).
// LDS:
//   sW  [64][132] floats (pad 4 -> stride 132 == 4 mod 32: conflict-free float4
//        reads indexed by lane h). Holds W2, then W3.
//   sY  [32][128]  activation buffer (out | rep concat). Reads during compute
//        are wave-uniform-address broadcasts.
//   sScr union: x1 staging [32][16] then pool partials [8][64].
__global__ __launch_bounds__(256, 2) void fused_mlp_maxpool(
    const float* __restrict__ X, const int* __restrict__ M,
    const float* __restrict__ W1, const float* __restrict__ B1,
    const float* __restrict__ W2, const float* __restrict__ B2,
    const float* __restrict__ W3, const float* __restrict__ B3,
    float* __restrict__ OUT)
{
    __shared__ __align__(16) float sW[kH * 33 * 4];   // 33792 B
    __shared__ __align__(16) float sY[kV * kK];       // 16384 B
    __shared__ __align__(16) float sScr[512];         //  2048 B
    __shared__ int sMask[kV];
    __shared__ int sAny;

    const int t  = threadIdx.x;
    const int bp = blockIdx.x;
    const int ha = t & 31;
    const int hb = ha + 32;
    const int vg = t >> 5;
    const int v0 = vg * 4;

    float4* sW4 = (float4*)sW;
    const float4* sY4 = (const float4*)sY;

    // ---- stage: W2 -> sW, x1 -> sScr, mask -> sMask ----
    {
        const float4* W2v = (const float4*)W2;   // 2048 float4
        #pragma unroll
        for (int j = 0; j < 8; ++j) {
            int q = t + j * 256;
            sW4[(q >> 5) * 33 + (q & 31)] = W2v[q];
        }
        const float4* Xv = (const float4*)(X + (size_t)bp * (kV * kF));
        if (t < 128) ((float4*)sScr)[t] = Xv[t];
        if (t < kV) sMask[t] = M[bp * kV + t];
        if (t == 0) sAny = 0;
    }
    __syncthreads();
    if (t < kV && sMask[t]) atomicOr(&sAny, 1);  // consumed >=1 barrier later

    float accA[4], accB[4];

    // ---- layer 1: (32x16)x(16x64), W1 rows held in registers ----
    {
        const float4* W1v = (const float4*)W1;
        float4 w1a[4], w1b[4];
        #pragma unroll
        for (int j = 0; j < 4; ++j) {
            w1a[j] = W1v[ha * 4 + j];
            w1b[j] = W1v[hb * 4 + j];
        }
        float ba = B1[ha], bb = B1[hb];
        const float4* sXv = (const float4*)sScr;
        #pragma unroll
        for (int i = 0; i < 4; ++i) {
            float a = ba, b = bb;
            #pragma unroll
            for (int j = 0; j < 4; ++j) {
                float4 xx = sXv[(v0 + i) * 4 + j];
                a = dot4(w1a[j], xx, a);
                b = dot4(w1b[j], xx, b);
            }
            accA[i] = a;
            accB[i] = b;
        }
    }

    // ---- layer 1 epilogue: mask, lrelu, pool, write out|rep ----
    {
        float pA = -INFINITY, pB = -INFINITY;
        float oA[4], oB[4];
        #pragma unroll
        for (int i = 0; i < 4; ++i) {
            bool m = sMask[v0 + i] != 0;
            float ya = lrelu(accA[i]), yb = lrelu(accB[i]);
            oA[i] = m ? ya : 0.f;
            oB[i] = m ? yb : 0.f;
            if (m) { pA = fmaxf(pA, ya); pB = fmaxf(pB, yb); }
        }
        __syncthreads();                 // all x1 reads done; sScr -> pool
        float* sPool = sScr;
        #pragma unroll
        for (int i = 0; i < 4; ++i) {
            sY[(v0 + i) * kK + ha] = oA[i];
            sY[(v0 + i) * kK + hb] = oB[i];
        }
        sPool[vg * kH + ha] = pA;
        sPool[vg * kH + hb] = pB;
        __syncthreads();
        float fA = -INFINITY, fB = -INFINITY;
        #pragma unroll
        for (int g = 0; g < 8; ++g) {
            fA = fmaxf(fA, sPool[g * kH + ha]);
            fB = fmaxf(fB, sPool[g * kH + hb]);
        }
        const bool any = (sAny != 0);
        fA = any ? fA : 0.f;
        fB = any ? fB : 0.f;
        #pragma unroll
        for (int i = 0; i < 4; ++i) {    // rep broadcast
            sY[(v0 + i) * kK + kH + ha] = fA;
            sY[(v0 + i) * kK + kH + hb] = fB;
        }
        __syncthreads();
    }

    // ---- layer 2: (32x128)x(128x64) from sW(=W2), sY ----
    {
        float ba = B2[ha], bb = B2[hb];
        #pragma unroll
        for (int i = 0; i < 4; ++i) { accA[i] = ba; accB[i] = bb; }
        const float4* wrA = sW4 + ha * 33;
        const float4* wrB = sW4 + hb * 33;
        #pragma unroll 8
        for (int kb = 0; kb < 32; ++kb) {
            float4 wA = wrA[kb];
            float4 wB = wrB[kb];
            #pragma unroll
            for (int i = 0; i < 4; ++i) {
                float4 xx = sY4[(v0 + i) * 32 + kb];
                accA[i] = dot4(wA, xx, accA[i]);
                accB[i] = dot4(wB, xx, accB[i]);
            }
        }
    }
    __syncthreads();                     // W2 + x2 reads complete

    // ---- stage W3 into sW (overlaps epilogue writes) ----
    {
        const float4* W3v = (const float4*)W3;
        #pragma unroll
        for (int j = 0; j < 8; ++j) {
            int q = t + j * 256;
            sW4[(q >> 5) * 33 + (q & 31)] = W3v[q];
        }
    }

    // ---- layer 2 epilogue ----
    {
        float pA = -INFINITY, pB = -INFINITY;
        float oA[4], oB[4];
        #pragma unroll
        for (int i = 0; i < 4; ++i) {
            bool m = sMask[v0 + i] != 0;
            float ya = lrelu(accA[i]), yb = lrelu(accB[i]);
            oA[i] = m ? ya : 0.f;
            oB[i] = m ? yb : 0.f;
            if (m) { pA = fmaxf(pA, ya); pB = fmaxf(pB, yb); }
        }
        float* sPool = sScr;
        #pragma unroll
        for (int i = 0; i < 4; ++i) {
            sY[(v0 + i) * kK + ha] = oA[i];
            sY[(v0 + i) * kK + hb] = oB[i];
        }
        sPool[vg * kH + ha] = pA;
        sPool[vg * kH + hb] = pB;
        __syncthreads();
        float fA = -INFINITY, fB = -INFINITY;
        #pragma unroll
        for (int g = 0; g < 8; ++g) {
            fA = fmaxf(fA, sPool[g * kH + ha]);
            fB = fmaxf(fB, sPool[g * kH + hb]);
        }
        const bool any = (sAny != 0);
        fA = any ? fA : 0.f;
        fB = any ? fB : 0.f;
        #pragma unroll
        for (int i = 0; i < 4; ++i) {
            sY[(v0 + i) * kK + kH + ha] = fA;
            sY[(v0 + i) * kK + kH + hb] = fB;
        }
        __syncthreads();
    }

    // ---- layer 3: only the pool is needed (final out == pool3) ----
    {
        float ba = B3[ha], bb = B3[hb];
        #pragma unroll
        for (int i = 0; i < 4; ++i) { accA[i] = ba; accB[i] = bb; }
        const float4* wrA = sW4 + ha * 33;
        const float4* wrB = sW4 + hb * 33;
        #pragma unroll 8
        for (int kb = 0; kb < 32; ++kb) {
            float4 wA = wrA[kb];
            float4 wB = wrB[kb];
            #pragma unroll
            for (int i = 0; i < 4; ++i) {
                float4 xx = sY4[(v0 + i) * 32 + kb];
                accA[i] = dot4(wA, xx, accA[i]);
                accB[i] = dot4(wB, xx, accB[i]);
            }
        }
        float pA = -INFINITY, pB = -INFINITY;
        #pragma unroll
        for (int i = 0; i < 4; ++i) {
            bool m = sMask[v0 + i] != 0;
            if (m) {
                pA = fmaxf(pA, lrelu(accA[i]));
                pB = fmaxf(pB, lrelu(accB[i]));
            }
        }
        float* sPool = sScr;   // last read was before the previous barrier
        sPool[vg * kH + ha] = pA;
        sPool[vg * kH + hb] = pB;
        __syncthreads();
        if (t < kH) {
            float m = -INFINITY;
            #pragma unroll
            for (int g = 0; g < 8; ++g) m = fmaxf(m, sPool[g * kH + t]);
            OUT[(size_t)bp * kH + t] = (sAny != 0) ? m : 0.f;
        }
    }
}
} // namespace

extern "C" void kernel_launch(void* const* d_in, const int* in_sizes, int n_in,
                              void* d_out, int out_size, void* d_ws, size_t ws_size,
                              hipStream_t stream) {
    (void)in_sizes; (void)n_in; (void)d_ws; (void)ws_size; (void)out_size;
    const float* X  = (const float*)d_in[0];
    const int*   M  = (const int*)d_in[1];   // bool mask passed as int32
    const float* W1 = (const float*)d_in[2];
    const float* B1 = (const float*)d_in[3];
    const float* W2 = (const float*)d_in[4];
    const float* B2 = (const float*)d_in[5];
    const float* W3 = (const float*)d_in[6];
    const float* B3 = (const float*)d_in[7];
    float* OUT = (float*)d_out;

    const int grid = 32 * 512;   // one block per (b,p)
    fused_mlp_maxpool<<<grid, 256, 0, stream>>>(X, M, W1, B1, W2, B2, W3, B3, OUT);
}

// Round 2
// 146.847 us; speedup vs baseline: 2.8071x; 2.8071x over previous
//
#include <hip/hip_runtime.h>
#include <hip/hip_bf16.h>
#include <math.h>

// (B,P,V,F,H) = (32,512,32,16,64).  Block = 2 (b,p) pairs, 256 threads = 4 waves.
// Wave w: bp_loc = w&1 (rows 32*bp_loc..+31 of the M=64 stack),
//         npair  = w>>1 (output cols 32*npair..+31).
// MFMA 16x16x32 bf16:  A[m=lane&15][k=quad*8+j], B[k=quad*8+j][n=lane&15],
//                      D[row=quad*4+reg][col=lane&15]   (m89/m120-verified layouts)
namespace {
constexpr int kV  = 32;
constexpr int kH  = 64;
constexpr int kKW = 128;    // 2H
constexpr int kXS = 136;    // shorts per x-buffer row (128 + 8 pad -> 17 float4s, odd)
constexpr int kWS = 136;    // shorts per W row
constexpr float kSlope = 0.01f;

typedef short bf16x8 __attribute__((ext_vector_type(8)));
typedef float f32x4  __attribute__((ext_vector_type(4)));

__device__ __forceinline__ float lrelu(float x) { return fmaxf(x, kSlope * x); }

__device__ __forceinline__ short2 cvt2bf(float a, float b) {
    union { __hip_bfloat162 h; short2 s; } u;
    u.h = __float22bfloat162_rn(float2{a, b});
    return u.s;
}
__device__ __forceinline__ short cvt1bf(float a) {
    union { __hip_bfloat16 h; short s; } u;
    u.h = __float2bfloat16(a);
    return u.s;
}

__device__ __forceinline__ void stageW(const float* __restrict__ Wg,
                                       short* __restrict__ sWp, int t) {
    const float4* Wv = (const float4*)Wg;          // 64x128 fp32 = 2048 float4
    #pragma unroll
    for (int j = 0; j < 8; ++j) {
        int q = t + j * 256;
        float4 f = Wv[q];
        int r = q >> 5, c = q & 31;
        short2 lo = cvt2bf(f.x, f.y), hi = cvt2bf(f.z, f.w);
        *(short4*)&sWp[r * kWS + c * 4] = make_short4(lo.x, lo.y, hi.x, hi.y);
    }
}

__global__ __launch_bounds__(256, 3) void fused_mlp_mfma(
    const float* __restrict__ X, const int* __restrict__ M,
    const float* __restrict__ W1, const float* __restrict__ B1,
    const float* __restrict__ W2, const float* __restrict__ B2,
    const float* __restrict__ W3, const float* __restrict__ B3,
    float* __restrict__ OUT)
{
    __shared__ __align__(16) short sX[2][64 * kXS];   // 2 x 17408 B
    __shared__ __align__(16) short sW[64 * kWS];      //     17408 B

    const int t      = threadIdx.x;
    const int w      = t >> 6;
    const int l      = t & 63;
    const int col    = l & 15;
    const int quad   = l >> 4;
    const int bp_loc = w & 1;
    const int npair  = w >> 1;
    const int nbase  = 32 * npair;
    const size_t bp0 = (size_t)blockIdx.x * 2;
    const size_t bpg = bp0 + bp_loc;

    // ---- stage W2 (bf16) ----
    stageW(W2, sW, t);

    // ---- per-lane mask bits: bit (mt*4+r) <-> v-row 16*mt + quad*4 + r ----
    unsigned mbits = 0;
    {
        const int* Mp = M + bpg * kV;
        #pragma unroll
        for (int mt = 0; mt < 2; ++mt)
            #pragma unroll
            for (int r = 0; r < 4; ++r)
                mbits |= (Mp[16 * mt + quad * 4 + r] ? 1u : 0u) << (mt * 4 + r);
    }
    const bool anyv = __any(mbits != 0) != 0;

    f32x4 acc[2][2];

    // ---- layer 1: frags straight from global, K=16 zero-padded to 32 ----
    {
        bf16x8 af[2], bf[2];
        #pragma unroll
        for (int nt = 0; nt < 2; ++nt) {
            bf16x8 v = {};
            if (quad < 2) {
                const float4* p = (const float4*)(W1 + ((size_t)(nbase + 16 * nt + col)) * 16 + quad * 8);
                float4 f0 = p[0], f1 = p[1];
                short2 a0 = cvt2bf(f0.x, f0.y), a1 = cvt2bf(f0.z, f0.w);
                short2 a2 = cvt2bf(f1.x, f1.y), a3 = cvt2bf(f1.z, f1.w);
                v[0]=a0.x; v[1]=a0.y; v[2]=a1.x; v[3]=a1.y;
                v[4]=a2.x; v[5]=a2.y; v[6]=a3.x; v[7]=a3.y;
            }
            bf[nt] = v;
        }
        #pragma unroll
        for (int mt = 0; mt < 2; ++mt) {
            bf16x8 v = {};
            if (quad < 2) {
                const float4* p = (const float4*)(X + (bpg * kV + 16 * mt + col) * 16 + quad * 8);
                float4 f0 = p[0], f1 = p[1];
                short2 a0 = cvt2bf(f0.x, f0.y), a1 = cvt2bf(f0.z, f0.w);
                short2 a2 = cvt2bf(f1.x, f1.y), a3 = cvt2bf(f1.z, f1.w);
                v[0]=a0.x; v[1]=a0.y; v[2]=a1.x; v[3]=a1.y;
                v[4]=a2.x; v[5]=a2.y; v[6]=a3.x; v[7]=a3.y;
            }
            af[mt] = v;
        }
        float bb[2] = { B1[nbase + col], B1[nbase + 16 + col] };
        #pragma unroll
        for (int mt = 0; mt < 2; ++mt)
            #pragma unroll
            for (int nt = 0; nt < 2; ++nt) {
                f32x4 c = { bb[nt], bb[nt], bb[nt], bb[nt] };
                acc[mt][nt] = __builtin_amdgcn_mfma_f32_16x16x32_bf16(af[mt], bf[nt], c, 0, 0, 0);
            }
    }

    // ---- epilogue: lrelu, mask, shuffle max-pool, write [out|rep] bf16 ----
    auto epilogue = [&](short* dst) {
        #pragma unroll
        for (int nt = 0; nt < 2; ++nt) {
            float pool = -INFINITY;
            float o[2][4];
            #pragma unroll
            for (int mt = 0; mt < 2; ++mt)
                #pragma unroll
                for (int r = 0; r < 4; ++r) {
                    float y = lrelu(acc[mt][nt][r]);
                    bool mk = (mbits >> (mt * 4 + r)) & 1;
                    o[mt][r] = mk ? y : 0.f;
                    pool = mk ? fmaxf(pool, y) : pool;
                }
            pool = fmaxf(pool, __shfl_xor(pool, 16));
            pool = fmaxf(pool, __shfl_xor(pool, 32));
            pool = anyv ? pool : 0.f;
            short pb = cvt1bf(pool);
            const int cgl = nbase + 16 * nt + col;
            #pragma unroll
            for (int mt = 0; mt < 2; ++mt) {
                int rbase = (32 * bp_loc + 16 * mt + quad * 4) * kXS;
                #pragma unroll
                for (int r = 0; r < 4; ++r) {
                    dst[rbase + r * kXS + cgl]      = cvt1bf(o[mt][r]);
                    dst[rbase + r * kXS + 64 + cgl] = pb;
                }
            }
        }
    };
    epilogue(sX[0]);

    __syncthreads();   // W2 staged + x2 visible

    // ---- layer 2: LDS frags, K=128 ----
    {
        float bb[2] = { B2[nbase + col], B2[nbase + 16 + col] };
        #pragma unroll
        for (int mt = 0; mt < 2; ++mt)
            #pragma unroll
            for (int nt = 0; nt < 2; ++nt)
                acc[mt][nt] = f32x4{ bb[nt], bb[nt], bb[nt], bb[nt] };
        #pragma unroll
        for (int ks = 0; ks < 4; ++ks) {
            const int ko = ks * 32 + quad * 8;
            bf16x8 a[2], b[2];
            #pragma unroll
            for (int mt = 0; mt < 2; ++mt)
                a[mt] = *(const bf16x8*)&sX[0][(32 * bp_loc + 16 * mt + col) * kXS + ko];
            #pragma unroll
            for (int nt = 0; nt < 2; ++nt)
                b[nt] = *(const bf16x8*)&sW[(nbase + 16 * nt + col) * kWS + ko];
            #pragma unroll
            for (int mt = 0; mt < 2; ++mt)
                #pragma unroll
                for (int nt = 0; nt < 2; ++nt)
                    acc[mt][nt] = __builtin_amdgcn_mfma_f32_16x16x32_bf16(a[mt], b[nt], acc[mt][nt], 0, 0, 0);
        }
    }
    epilogue(sX[1]);   // x3 writes: disjoint region, safe before barrier

    __syncthreads();   // all W2/x2 reads complete
    stageW(W3, sW, t);
    __syncthreads();   // W3 visible

    // ---- layer 3: only the pool survives (out == pool3) ----
    {
        float bb[2] = { B3[nbase + col], B3[nbase + 16 + col] };
        #pragma unroll
        for (int mt = 0; mt < 2; ++mt)
            #pragma unroll
            for (int nt = 0; nt < 2; ++nt)
                acc[mt][nt] = f32x4{ bb[nt], bb[nt], bb[nt], bb[nt] };
        #pragma unroll
        for (int ks = 0; ks < 4; ++ks) {
            const int ko = ks * 32 + quad * 8;
            bf16x8 a[2], b[2];
            #pragma unroll
            for (int mt = 0; mt < 2; ++mt)
                a[mt] = *(const bf16x8*)&sX[1][(32 * bp_loc + 16 * mt + col) * kXS + ko];
            #pragma unroll
            for (int nt = 0; nt < 2; ++nt)
                b[nt] = *(const bf16x8*)&sW[(nbase + 16 * nt + col) * kWS + ko];
            #pragma unroll
            for (int mt = 0; mt < 2; ++mt)
                #pragma unroll
                for (int nt = 0; nt < 2; ++nt)
                    acc[mt][nt] = __builtin_amdgcn_mfma_f32_16x16x32_bf16(a[mt], b[nt], acc[mt][nt], 0, 0, 0);
        }
        #pragma unroll
        for (int nt = 0; nt < 2; ++nt) {
            float pool = -INFINITY;
            #pragma unroll
            for (int mt = 0; mt < 2; ++mt)
                #pragma unroll
                for (int r = 0; r < 4; ++r) {
                    float y = lrelu(acc[mt][nt][r]);
                    bool mk = (mbits >> (mt * 4 + r)) & 1;
                    pool = mk ? fmaxf(pool, y) : pool;
                }
            pool = fmaxf(pool, __shfl_xor(pool, 16));
            pool = fmaxf(pool, __shfl_xor(pool, 32));
            pool = anyv ? pool : 0.f;
            if (quad == 0)
                OUT[bpg * kH + nbase + 16 * nt + col] = pool;
        }
    }
}
} // namespace

extern "C" void kernel_launch(void* const* d_in, const int* in_sizes, int n_in,
                              void* d_out, int out_size, void* d_ws, size_t ws_size,
                              hipStream_t stream) {
    (void)in_sizes; (void)n_in; (void)d_ws; (void)ws_size; (void)out_size;
    const float* X  = (const float*)d_in[0];
    const int*   M  = (const int*)d_in[1];
    const float* W1 = (const float*)d_in[2];
    const float* B1 = (const float*)d_in[3];
    const float* W2 = (const float*)d_in[4];
    const float* B2 = (const float*)d_in[5];
    const float* W3 = (const float*)d_in[6];
    const float* B3 = (const float*)d_in[7];
    float* OUT = (float*)d_out;

    const int grid = (32 * 512) / 2;   // 2 (b,p) pairs per block
    fused_mlp_mfma<<<grid, 256, 0, stream>>>(X, M, W1, B1, W2, B2, W3, B3, OUT);
}